// Round 1
// baseline (989.197 us; speedup 1.0000x reference)
//
#include <hip/hip_runtime.h>
#include <hip/hip_bf16.h>
#include <math.h>

// Problem constants
constexpr int kN    = 8192;
constexpr int kR    = 3;
constexpr int kE    = 262144;
constexpr int kIn   = 128;
constexpr int kOut  = 64;
constexpr int kHead = 4;
constexpr int kD    = 256;   // kOut * kHead

// ---------------------------------------------------------------------------
// K1: per-node precompute.
// block = 256 threads, one block per node.
//  - sproj[t] = feat[n]@Wd[:,t] + bd[t]
//  - p_src[n] = sproj . (w1+w3), p_dst[n] = sproj . (w2-w3)  (block reduce)
//  - for each r: h_r[n,t] = feat[n]@Ww[r][:,t] + bw[r][t]  (stored)
//      qsrc[r][n][head] = sum_d h[n,head*64+d]*Wa[r][d]     (wave reduce)
//      qdst[r][n][head] = sum_d h[n,head*64+d]*Wa[r][64+d]
// ---------------------------------------------------------------------------
__global__ __launch_bounds__(256) void k_node_pre(
    const float* __restrict__ feat, const float* __restrict__ Wd,
    const float* __restrict__ bd,   const float* __restrict__ Wf,
    const float* __restrict__ Ww,   const float* __restrict__ bw,
    const float* __restrict__ Wa,
    float* __restrict__ p_src, float* __restrict__ p_dst,
    float* __restrict__ qsrc,  float* __restrict__ qdst,
    float* __restrict__ hbuf)
{
    const int n = blockIdx.x, t = threadIdx.x;
    __shared__ float f[kIn];
    __shared__ float2 red[256];

    if (t < kIn) f[t] = feat[n * kIn + t];
    __syncthreads();

    // sproj column t
    float sp = bd[t];
    #pragma unroll 8
    for (int k = 0; k < kIn; ++k) sp += f[k] * Wd[k * kD + t];

    const float w13 = Wf[t]        + Wf[2 * kD + t];
    const float w23 = Wf[kD + t]   - Wf[2 * kD + t];
    red[t] = make_float2(sp * w13, sp * w23);
    __syncthreads();
    for (int s = 128; s > 0; s >>= 1) {
        if (t < s) { red[t].x += red[t + s].x; red[t].y += red[t + s].y; }
        __syncthreads();
    }
    if (t == 0) { p_src[n] = red[0].x; p_dst[n] = red[0].y; }

    const int head = t >> 6, lane = t & 63;
    for (int r = 0; r < kR; ++r) {
        float hv = bw[r * kD + t];
        const float* W = Ww + (size_t)r * kIn * kD;
        #pragma unroll 8
        for (int k = 0; k < kIn; ++k) hv += f[k] * W[k * kD + t];
        hbuf[(size_t)r * kN * kD + (size_t)n * kD + t] = hv;

        float c1 = hv * Wa[r * 2 * kOut + lane];
        float c2 = hv * Wa[r * 2 * kOut + kOut + lane];
        for (int off = 32; off > 0; off >>= 1) {
            c1 += __shfl_down(c1, off);
            c2 += __shfl_down(c2, off);
        }
        if (lane == 0) {
            qsrc[(size_t)r * kN * kHead + n * kHead + head] = c1;
            qdst[(size_t)r * kN * kHead + n * kHead + head] = c2;
        }
    }
}

// ---------------------------------------------------------------------------
// K2a: degree histogram over dst
// ---------------------------------------------------------------------------
__global__ void k_hist(const int* __restrict__ dst, int* __restrict__ deg)
{
    int e = blockIdx.x * blockDim.x + threadIdx.x;
    if (e < kE) atomicAdd(&deg[dst[e]], 1);
}

// ---------------------------------------------------------------------------
// K2b: exclusive scan of deg[0..8191] -> rowstart.  Single block, 1024 thr.
// ---------------------------------------------------------------------------
__global__ __launch_bounds__(1024) void k_scan(
    const int* __restrict__ deg, int* __restrict__ rowstart)
{
    __shared__ int lds[1024];
    const int t = threadIdx.x;
    int v[8];
    int s = 0;
    #pragma unroll
    for (int k = 0; k < 8; ++k) v[k] = deg[t * 8 + k];
    #pragma unroll
    for (int k = 0; k < 8; ++k) { int tmp = s; s += v[k]; v[k] = tmp; }
    lds[t] = s;
    __syncthreads();
    for (int off = 1; off < 1024; off <<= 1) {
        int x = 0;
        if (t >= off) x = lds[t - off];
        __syncthreads();
        if (t >= off) lds[t] += x;
        __syncthreads();
    }
    const int pre = (t == 0) ? 0 : lds[t - 1];
    #pragma unroll
    for (int k = 0; k < 8; ++k) rowstart[t * 8 + k] = pre + v[k];
}

// ---------------------------------------------------------------------------
// K2c: scatter edges into dst-sorted order; compute sign and alpha per edge.
// ---------------------------------------------------------------------------
__global__ void k_scatter(
    const int* __restrict__ src_arr, const int* __restrict__ dst_arr,
    const float* __restrict__ p_src, const float* __restrict__ p_dst,
    const float* __restrict__ qsrc,  const float* __restrict__ qdst,  // offset by r
    const float* __restrict__ bf,    const float* __restrict__ ba, int r,
    const int* __restrict__ rowstart, int* __restrict__ cursor,
    int* __restrict__ srcs_s, float* __restrict__ sign_s,
    float4* __restrict__ alpha_s)
{
    int e = blockIdx.x * blockDim.x + threadIdx.x;
    if (e >= kE) return;
    const int s = src_arr[e], d = dst_arr[e];
    const float sg = tanhf(p_src[s] + p_dst[d] + bf[0]);
    const float bar = ba[r];
    float4 a;
    float* ap = &a.x;
    #pragma unroll
    for (int h = 0; h < kHead; ++h) {
        float x = sg * qsrc[s * kHead + h] + qdst[d * kHead + h] + bar;
        ap[h] = (x > 0.f) ? x : 0.01f * x;   // leaky_relu(0.01)
    }
    const int pos = rowstart[d] + atomicAdd(&cursor[d], 1);
    srcs_s[pos] = s;
    sign_s[pos] = sg;
    alpha_s[pos] = a;
}

// ---------------------------------------------------------------------------
// K3: per-node segment softmax + attention-weighted aggregation (no atomics).
// block = 256 threads = (head = t>>6, d = t&63).
// ---------------------------------------------------------------------------
__global__ __launch_bounds__(256) void k_node_agg(
    const int* __restrict__ deg, const int* __restrict__ rowstart,
    const int* __restrict__ srcs_s, const float* __restrict__ sign_s,
    const float4* __restrict__ alpha_s,
    const float* __restrict__ hr,   // offset by r
    float* __restrict__ hcat, int r)
{
    const int n = blockIdx.x, t = threadIdx.x;
    const int dg = deg[n], start = rowstart[n];
    __shared__ float4 red4[256];
    __shared__ float lds[256];

    if (dg == 0) {
        if (t < kOut) hcat[(size_t)n * (kR * kOut) + r * kOut + t] = 0.f;
        return;
    }

    // pass 1: per-head max over this node's edges
    float4 mx = make_float4(-INFINITY, -INFINITY, -INFINITY, -INFINITY);
    for (int i = t; i < dg; i += 256) {
        float4 a = alpha_s[start + i];
        mx.x = fmaxf(mx.x, a.x); mx.y = fmaxf(mx.y, a.y);
        mx.z = fmaxf(mx.z, a.z); mx.w = fmaxf(mx.w, a.w);
    }
    red4[t] = mx;
    __syncthreads();
    for (int s = 128; s > 0; s >>= 1) {
        if (t < s) {
            float4 o = red4[t + s];
            red4[t].x = fmaxf(red4[t].x, o.x); red4[t].y = fmaxf(red4[t].y, o.y);
            red4[t].z = fmaxf(red4[t].z, o.z); red4[t].w = fmaxf(red4[t].w, o.w);
        }
        __syncthreads();
    }
    const float4 mm = red4[0];
    const int head = t >> 6;
    const float m_h = (head == 0) ? mm.x : (head == 1) ? mm.y : (head == 2) ? mm.z : mm.w;

    // pass 2: ew = exp(alpha-m); denom per head; acc per (head,d) column
    const float* af = (const float*)alpha_s;
    float acc = 0.f, dsum = 0.f;
    for (int i = 0; i < dg; ++i) {
        const int pos = start + i;
        const float sg = sign_s[pos];
        const float a  = af[(size_t)pos * 4 + head];
        const float ew = __expf(a - m_h);
        dsum += ew;
        const int s = srcs_s[pos];
        acc += ew * sg * hr[(size_t)s * kD + t];
    }
    lds[t] = acc / dsum;
    __syncthreads();
    if (t < kOut) {
        hcat[(size_t)n * (kR * kOut) + r * kOut + t] =
            lds[t] + lds[t + 64] + lds[t + 128] + lds[t + 192];
    }
}

// ---------------------------------------------------------------------------
// K4: h_out = hcat @ Wl + bl.  one wave per node.
// ---------------------------------------------------------------------------
__global__ __launch_bounds__(64) void k_hout(
    const float* __restrict__ hcat, const float* __restrict__ Wl,
    const float* __restrict__ bl, float* __restrict__ out)
{
    const int n = blockIdx.x, t = threadIdx.x;
    __shared__ float row[kR * kOut];
    for (int k = t; k < kR * kOut; k += 64) row[k] = hcat[(size_t)n * (kR * kOut) + k];
    __syncthreads();
    float acc = bl[t];
    #pragma unroll 8
    for (int k = 0; k < kR * kOut; ++k) acc += row[k] * Wl[k * kOut + t];
    out[(size_t)n * kOut + t] = acc;
}

// ---------------------------------------------------------------------------
// K5: y_hat = rownorm(bi_adj * adj_mask) @ labels_mat.  One block per row.
// Dominant memory-bound pass: reads 2 * 32KB per row (512 MB total).
// ---------------------------------------------------------------------------
__global__ __launch_bounds__(256) void k_yhat(
    const float* __restrict__ bi, const float* __restrict__ mask,
    const float* __restrict__ labels, float* __restrict__ out)
{
    const int n = blockIdx.x, t = threadIdx.x;
    const float4* b4 = (const float4*)(bi   + (size_t)n * kN);
    const float4* m4 = (const float4*)(mask + (size_t)n * kN);
    const float4* l4 = (const float4*)labels;
    float ss = 0.f, y0 = 0.f, y1 = 0.f;
    for (int j = t; j < kN / 4; j += 256) {
        const float4 b = b4[j], m = m4[j];
        const float4 la = l4[2 * j], lb = l4[2 * j + 1];
        const float t0 = b.x * m.x, t1 = b.y * m.y, t2 = b.z * m.z, t3 = b.w * m.w;
        ss += fabsf(t0) + fabsf(t1) + fabsf(t2) + fabsf(t3);
        y0 += t0 * la.x + t1 * la.z + t2 * lb.x + t3 * lb.z;
        y1 += t0 * la.y + t1 * la.w + t2 * lb.y + t3 * lb.w;
    }
    __shared__ float4 red[256];
    red[t] = make_float4(ss, y0, y1, 0.f);
    __syncthreads();
    for (int s = 128; s > 0; s >>= 1) {
        if (t < s) {
            red[t].x += red[t + s].x; red[t].y += red[t + s].y; red[t].z += red[t + s].z;
        }
        __syncthreads();
    }
    if (t == 0) {
        const float s = fmaxf(red[0].x, 1e-12f);
        out[(size_t)n * 2]     = red[0].y / s;
        out[(size_t)n * 2 + 1] = red[0].z / s;
    }
}

// ---------------------------------------------------------------------------
extern "C" void kernel_launch(void* const* d_in, const int* in_sizes, int n_in,
                              void* d_out, int out_size, void* d_ws, size_t ws_size,
                              hipStream_t stream)
{
    const float* feat   = (const float*)d_in[0];
    const float* labels = (const float*)d_in[1];
    const float* bi     = (const float*)d_in[2];
    const float* mask   = (const float*)d_in[3];
    const float* Wd     = (const float*)d_in[4];
    const float* bd     = (const float*)d_in[5];
    const float* Wf     = (const float*)d_in[6];
    const float* bf     = (const float*)d_in[7];
    const float* Ww     = (const float*)d_in[8];
    const float* bw     = (const float*)d_in[9];
    const float* Wa     = (const float*)d_in[10];
    const float* ba     = (const float*)d_in[11];
    const float* Wl     = (const float*)d_in[12];
    const float* bl     = (const float*)d_in[13];
    const int*   edges  = (const int*)d_in[14];
    float* out = (float*)d_out;

    // workspace layout (all counts are multiples of 4 elements; base is 256B aligned)
    float* w = (float*)d_ws;
    float* p_src  = w; w += kN;
    float* p_dst  = w; w += kN;
    float* qsrc   = w; w += (size_t)kR * kN * kHead;
    float* qdst   = w; w += (size_t)kR * kN * kHead;
    float* hbuf   = w; w += (size_t)kR * kN * kD;
    float* hcat   = w; w += (size_t)kN * kR * kOut;
    float* sign_s = w; w += kE;
    float* alpha_s= w; w += (size_t)kE * 4;
    int* srcs_s   = (int*)w; w += kE;
    int* deg      = (int*)w; w += kN;
    int* rowstart = (int*)w; w += kN;
    int* cursor   = (int*)w; w += kN;

    k_node_pre<<<kN, 256, 0, stream>>>(feat, Wd, bd, Wf, Ww, bw, Wa,
                                       p_src, p_dst, qsrc, qdst, hbuf);

    for (int r = 0; r < kR; ++r) {
        const int* src_arr = edges + (size_t)r * 2 * kE;
        const int* dst_arr = src_arr + kE;
        hipMemsetAsync(deg,    0, kN * sizeof(int), stream);
        hipMemsetAsync(cursor, 0, kN * sizeof(int), stream);
        k_hist<<<kE / 256, 256, 0, stream>>>(dst_arr, deg);
        k_scan<<<1, 1024, 0, stream>>>(deg, rowstart);
        k_scatter<<<kE / 256, 256, 0, stream>>>(
            src_arr, dst_arr, p_src, p_dst,
            qsrc + (size_t)r * kN * kHead, qdst + (size_t)r * kN * kHead,
            bf, ba, r, rowstart, cursor, srcs_s, sign_s, (float4*)alpha_s);
        k_node_agg<<<kN, 256, 0, stream>>>(
            deg, rowstart, srcs_s, sign_s, (const float4*)alpha_s,
            hbuf + (size_t)r * kN * kD, hcat, r);
    }

    k_hout<<<kN, 64, 0, stream>>>(hcat, Wl, bl, out);
    k_yhat<<<kN, 256, 0, stream>>>(bi, mask, labels, out + (size_t)kN * kOut);
}

// Round 3
// 870.267 us; speedup vs baseline: 1.1367x; 1.1367x over previous
//
#include <hip/hip_runtime.h>
#include <hip/hip_bf16.h>
#include <math.h>

// Problem constants
constexpr int kN    = 8192;
constexpr int kR    = 3;
constexpr int kE    = 262144;
constexpr int kIn   = 128;
constexpr int kOut  = 64;
constexpr int kHead = 4;
constexpr int kD    = 256;   // kOut * kHead
constexpr int NB    = 16;    // nodes per block in k_node_pre
constexpr int kCols = 2 + 2 * kR * kHead;  // 26 fused projection columns

// ---------------------------------------------------------------------------
// K0: fold the small projections into 26 feat-space vectors.
//   p_src = feat@(Wd@w13)+bd.w13 ; qsrc[r,h] = feat@(Ww_r[:,h]@Wa_r)+bw.Wa ...
// V rows: 0=u_src, 1=u_dst, 2+r*4+h=vsrc, 14+r*4+h=vdst.  C[26] = constants.
// ---------------------------------------------------------------------------
__global__ __launch_bounds__(256) void k_prep(
    const float* __restrict__ Wd, const float* __restrict__ bd,
    const float* __restrict__ Wf, const float* __restrict__ Ww,
    const float* __restrict__ bw, const float* __restrict__ Wa,
    float* __restrict__ V, float* __restrict__ C)
{
    const int t = threadIdx.x;
    for (int task = t; task < kCols * kIn; task += 256) {
        const int row = task >> 7;   // /128
        const int k   = task & 127;
        float s = 0.f;
        if (row < 2) {
            for (int c = 0; c < kD; ++c) {
                const float w = (row == 0) ? (Wf[c] + Wf[2 * kD + c])
                                           : (Wf[kD + c] - Wf[2 * kD + c]);
                s += Wd[k * kD + c] * w;
            }
        } else {
            const int idx = row - 2;
            const int src = idx < kR * kHead;
            const int rel = (src ? idx : idx - kR * kHead) >> 2;
            const int h   = (src ? idx : idx - kR * kHead) & 3;
            const float* wwk = Ww + ((size_t)rel * kIn + k) * kD + h * kOut;
            const float* wa  = Wa + rel * 2 * kOut + (src ? 0 : kOut);
            for (int d = 0; d < kOut; ++d) s += wwk[d] * wa[d];
        }
        V[row * kIn + k] = s;
    }
    if (t < kCols) {
        const int row = t;
        float s = 0.f;
        if (row < 2) {
            for (int c = 0; c < kD; ++c) {
                const float w = (row == 0) ? (Wf[c] + Wf[2 * kD + c])
                                           : (Wf[kD + c] - Wf[2 * kD + c]);
                s += bd[c] * w;
            }
        } else {
            const int idx = row - 2;
            const int src = idx < kR * kHead;
            const int rel = (src ? idx : idx - kR * kHead) >> 2;
            const int h   = (src ? idx : idx - kR * kHead) & 3;
            const float* bwr = bw + rel * kD + h * kOut;
            const float* wa  = Wa + rel * 2 * kOut + (src ? 0 : kOut);
            for (int d = 0; d < kOut; ++d) s += bwr[d] * wa[d];
        }
        C[row] = s;
    }
}

// ---------------------------------------------------------------------------
// K1: h_r = feat@Ww[r]+bw[r] for NB nodes per block + the 26 fused columns.
// 256 threads = output column t; 16 accumulators (one per node).
// ---------------------------------------------------------------------------
__global__ __launch_bounds__(256) void k_node_pre(
    const float* __restrict__ feat, const float* __restrict__ Ww,
    const float* __restrict__ bw,   const float* __restrict__ V,
    const float* __restrict__ C,
    float* __restrict__ hbuf, float* __restrict__ p_src, float* __restrict__ p_dst,
    float* __restrict__ qsrc, float* __restrict__ qdst)
{
    const int nb = blockIdx.x * NB;
    const int t  = threadIdx.x;
    __shared__ float f[NB][kIn];   // 8 KB

    const float4* fg = (const float4*)(feat + (size_t)nb * kIn);
    float4* fl = (float4*)f;
    for (int i = t; i < NB * kIn / 4; i += 256) fl[i] = fg[i];
    __syncthreads();

    for (int r = 0; r < kR; ++r) {
        const float* W = Ww + (size_t)r * kIn * kD;
        const float b = bw[r * kD + t];
        float acc[NB];
        #pragma unroll
        for (int j = 0; j < NB; ++j) acc[j] = b;
        for (int k4 = 0; k4 < kIn / 4; ++k4) {
            const float w0 = W[(k4 * 4 + 0) * kD + t];
            const float w1 = W[(k4 * 4 + 1) * kD + t];
            const float w2 = W[(k4 * 4 + 2) * kD + t];
            const float w3 = W[(k4 * 4 + 3) * kD + t];
            #pragma unroll
            for (int j = 0; j < NB; ++j) {
                const float4 fv = *(const float4*)&f[j][k4 * 4];
                acc[j] += fv.x * w0 + fv.y * w1 + fv.z * w2 + fv.w * w3;
            }
        }
        float* hb = hbuf + ((size_t)r * kN + nb) * kD + t;
        #pragma unroll
        for (int j = 0; j < NB; ++j) hb[(size_t)j * kD] = acc[j];
    }

    // fused small projections: 16 nodes x 26 cols = 416 dot-128 tasks
    for (int task = t; task < NB * kCols; task += 256) {
        const int j = task / kCols, col = task % kCols;
        const float* v = V + col * kIn;
        float s = C[col];
        for (int k4 = 0; k4 < kIn / 4; ++k4) {
            const float4 fv = *(const float4*)&f[j][k4 * 4];
            const float4 vv = *(const float4*)&v[k4 * 4];
            s += fv.x * vv.x + fv.y * vv.y + fv.z * vv.z + fv.w * vv.w;
        }
        const int n = nb + j;
        if (col == 0)      p_src[n] = s;
        else if (col == 1) p_dst[n] = s;
        else if (col < 2 + kR * kHead) {
            const int idx = col - 2;
            qsrc[((size_t)(idx >> 2) * kN + n) * kHead + (idx & 3)] = s;
        } else {
            const int idx = col - 2 - kR * kHead;
            qdst[((size_t)(idx >> 2) * kN + n) * kHead + (idx & 3)] = s;
        }
    }
}

// ---------------------------------------------------------------------------
// K2a: degree histogram over dst, all relations (gridDim.y = r)
// ---------------------------------------------------------------------------
__global__ void k_hist(const int* __restrict__ edges, int* __restrict__ deg)
{
    const int r = blockIdx.y;
    const int e = blockIdx.x * blockDim.x + threadIdx.x;
    const int d = edges[(size_t)r * 2 * kE + kE + e];
    atomicAdd(&deg[r * kN + d], 1);
}

// ---------------------------------------------------------------------------
// K2b: exclusive scan of deg[r][0..8191] -> rowstart[r].  One block per r.
// ---------------------------------------------------------------------------
__global__ __launch_bounds__(1024) void k_scan(
    const int* __restrict__ deg_all, int* __restrict__ rowstart_all)
{
    const int r = blockIdx.x;
    const int* deg = deg_all + r * kN;
    int* rowstart = rowstart_all + r * kN;
    __shared__ int lds[1024];
    const int t = threadIdx.x;
    int v[8];
    int s = 0;
    #pragma unroll
    for (int k = 0; k < 8; ++k) v[k] = deg[t * 8 + k];
    #pragma unroll
    for (int k = 0; k < 8; ++k) { int tmp = s; s += v[k]; v[k] = tmp; }
    lds[t] = s;
    __syncthreads();
    for (int off = 1; off < 1024; off <<= 1) {
        int x = 0;
        if (t >= off) x = lds[t - off];
        __syncthreads();
        if (t >= off) lds[t] += x;
        __syncthreads();
    }
    const int pre = (t == 0) ? 0 : lds[t - 1];
    #pragma unroll
    for (int k = 0; k < 8; ++k) rowstart[t * 8 + k] = pre + v[k];
}

// ---------------------------------------------------------------------------
// K2c: scatter edges into dst-sorted order; compute sign and alpha per edge.
// ---------------------------------------------------------------------------
__global__ void k_scatter(
    const int* __restrict__ edges,
    const float* __restrict__ p_src, const float* __restrict__ p_dst,
    const float* __restrict__ qsrc_all, const float* __restrict__ qdst_all,
    const float* __restrict__ bf, const float* __restrict__ ba,
    const int* __restrict__ rowstart, int* __restrict__ cursor,
    int* __restrict__ srcs_s, float* __restrict__ sign_s,
    float4* __restrict__ alpha_s)
{
    const int r = blockIdx.y;
    const int e = blockIdx.x * blockDim.x + threadIdx.x;
    const int s = edges[(size_t)r * 2 * kE + e];
    const int d = edges[(size_t)r * 2 * kE + kE + e];
    const float sg = tanhf(p_src[s] + p_dst[d] + bf[0]);
    const float bar = ba[r];
    const float4 qs = *(const float4*)&qsrc_all[((size_t)r * kN + s) * kHead];
    const float4 qd = *(const float4*)&qdst_all[((size_t)r * kN + d) * kHead];
    float4 a;
    a.x = sg * qs.x + qd.x + bar;
    a.y = sg * qs.y + qd.y + bar;
    a.z = sg * qs.z + qd.z + bar;
    a.w = sg * qs.w + qd.w + bar;
    a.x = (a.x > 0.f) ? a.x : 0.01f * a.x;
    a.y = (a.y > 0.f) ? a.y : 0.01f * a.y;
    a.z = (a.z > 0.f) ? a.z : 0.01f * a.z;
    a.w = (a.w > 0.f) ? a.w : 0.01f * a.w;
    const int pos = rowstart[r * kN + d] + atomicAdd(&cursor[r * kN + d], 1);
    srcs_s[(size_t)r * kE + pos] = s;
    sign_s[(size_t)r * kE + pos] = sg;
    alpha_s[(size_t)r * kE + pos] = a;
}

// ---------------------------------------------------------------------------
// K3: per-node segment softmax + attention-weighted aggregation (no atomics).
// Edge data cached in LDS between passes.  grid = (kN, kR).
// ---------------------------------------------------------------------------
__global__ __launch_bounds__(256) void k_node_agg(
    const int* __restrict__ deg, const int* __restrict__ rowstart,
    const int* __restrict__ srcs_all, const float* __restrict__ sign_all,
    const float4* __restrict__ alpha_all, const float* __restrict__ hbuf,
    float* __restrict__ hcat)
{
    const int r = blockIdx.y;
    const int n = blockIdx.x, t = threadIdx.x;
    const int dg = deg[r * kN + n], start = rowstart[r * kN + n];
    const float* hr = hbuf + (size_t)r * kN * kD;
    const int* srcs = srcs_all + (size_t)r * kE;
    const float* sgn = sign_all + (size_t)r * kE;
    const float4* al = alpha_all + (size_t)r * kE;

    constexpr int CAP = 128;
    __shared__ float4 red4[256];
    __shared__ float4 s_al[CAP];
    __shared__ float  s_sg[CAP];
    __shared__ int    s_sr[CAP];
    __shared__ float  lds[256];

    if (dg == 0) {
        if (t < kOut) hcat[(size_t)n * (kR * kOut) + r * kOut + t] = 0.f;
        return;
    }

    // pass 1: per-head max; stash edge data in LDS
    float4 mx = make_float4(-INFINITY, -INFINITY, -INFINITY, -INFINITY);
    for (int i = t; i < dg; i += 256) {
        const float4 a = al[start + i];
        if (i < CAP) {
            s_al[i] = a;
            s_sg[i] = sgn[start + i];
            s_sr[i] = srcs[start + i];
        }
        mx.x = fmaxf(mx.x, a.x); mx.y = fmaxf(mx.y, a.y);
        mx.z = fmaxf(mx.z, a.z); mx.w = fmaxf(mx.w, a.w);
    }
    red4[t] = mx;
    __syncthreads();
    for (int s = 128; s > 0; s >>= 1) {
        if (t < s) {
            const float4 o = red4[t + s];
            red4[t].x = fmaxf(red4[t].x, o.x); red4[t].y = fmaxf(red4[t].y, o.y);
            red4[t].z = fmaxf(red4[t].z, o.z); red4[t].w = fmaxf(red4[t].w, o.w);
        }
        __syncthreads();
    }
    const float4 mm = red4[0];
    const int head = t >> 6;
    const float m_h = (head == 0) ? mm.x : (head == 1) ? mm.y
                    : (head == 2) ? mm.z : mm.w;

    // pass 2: exp, denom, weighted accumulation (edge data from LDS)
    float acc = 0.f, dsum = 0.f;
    const int m = (dg < CAP) ? dg : CAP;
    for (int i = 0; i < m; ++i) {
        const float a  = ((const float*)&s_al[i])[head];
        const float ew = __expf(a - m_h);
        dsum += ew;
        acc += ew * s_sg[i] * hr[(size_t)s_sr[i] * kD + t];
    }
    for (int i = CAP; i < dg; ++i) {   // overflow fallback (rare)
        const int pos = start + i;
        const float a  = ((const float*)&al[pos])[head];
        const float ew = __expf(a - m_h);
        dsum += ew;
        acc += ew * sgn[pos] * hr[(size_t)srcs[pos] * kD + t];
    }
    lds[t] = acc / dsum;
    __syncthreads();
    if (t < kOut) {
        hcat[(size_t)n * (kR * kOut) + r * kOut + t] =
            lds[t] + lds[t + 64] + lds[t + 128] + lds[t + 192];
    }
}

// ---------------------------------------------------------------------------
// K4: h_out = hcat @ Wl + bl.  one wave per node.
// ---------------------------------------------------------------------------
__global__ __launch_bounds__(64) void k_hout(
    const float* __restrict__ hcat, const float* __restrict__ Wl,
    const float* __restrict__ bl, float* __restrict__ out)
{
    const int n = blockIdx.x, t = threadIdx.x;
    __shared__ float row[kR * kOut];
    for (int k = t; k < kR * kOut; k += 64) row[k] = hcat[(size_t)n * (kR * kOut) + k];
    __syncthreads();
    float acc = bl[t];
    #pragma unroll 8
    for (int k = 0; k < kR * kOut; ++k) acc += row[k] * Wl[k * kOut + t];
    out[(size_t)n * kOut + t] = acc;
}

// ---------------------------------------------------------------------------
// K5: y_hat = rownorm(bi_adj * adj_mask) @ labels_mat.  One block per row.
// Structural floor: 512 MB of unique reads.
// ---------------------------------------------------------------------------
__global__ __launch_bounds__(256) void k_yhat(
    const float* __restrict__ bi, const float* __restrict__ mask,
    const float* __restrict__ labels, float* __restrict__ out)
{
    const int n = blockIdx.x, t = threadIdx.x;
    const float4* b4 = (const float4*)(bi   + (size_t)n * kN);
    const float4* m4 = (const float4*)(mask + (size_t)n * kN);
    const float4* l4 = (const float4*)labels;
    float ss = 0.f, y0 = 0.f, y1 = 0.f;
    for (int j = t; j < kN / 4; j += 256) {
        const float4 b = b4[j], m = m4[j];
        const float4 la = l4[2 * j], lb = l4[2 * j + 1];
        const float t0 = b.x * m.x, t1 = b.y * m.y, t2 = b.z * m.z, t3 = b.w * m.w;
        ss += fabsf(t0) + fabsf(t1) + fabsf(t2) + fabsf(t3);
        y0 += t0 * la.x + t1 * la.z + t2 * lb.x + t3 * lb.z;
        y1 += t0 * la.y + t1 * la.w + t2 * lb.y + t3 * lb.w;
    }
    __shared__ float4 red[256];
    red[t] = make_float4(ss, y0, y1, 0.f);
    __syncthreads();
    for (int s = 128; s > 0; s >>= 1) {
        if (t < s) {
            red[t].x += red[t + s].x; red[t].y += red[t + s].y; red[t].z += red[t + s].z;
        }
        __syncthreads();
    }
    if (t == 0) {
        const float s = fmaxf(red[0].x, 1e-12f);
        out[(size_t)n * 2]     = red[0].y / s;
        out[(size_t)n * 2 + 1] = red[0].z / s;
    }
}

// ---------------------------------------------------------------------------
extern "C" void kernel_launch(void* const* d_in, const int* in_sizes, int n_in,
                              void* d_out, int out_size, void* d_ws, size_t ws_size,
                              hipStream_t stream)
{
    const float* feat   = (const float*)d_in[0];
    const float* labels = (const float*)d_in[1];
    const float* bi     = (const float*)d_in[2];
    const float* mask   = (const float*)d_in[3];
    const float* Wd     = (const float*)d_in[4];
    const float* bd     = (const float*)d_in[5];
    const float* Wf     = (const float*)d_in[6];
    const float* bf     = (const float*)d_in[7];
    const float* Ww     = (const float*)d_in[8];
    const float* bw     = (const float*)d_in[9];
    const float* Wa     = (const float*)d_in[10];
    const float* ba     = (const float*)d_in[11];
    const float* Wl     = (const float*)d_in[12];
    const float* bl     = (const float*)d_in[13];
    const int*   edges  = (const int*)d_in[14];
    float* out = (float*)d_out;

    // workspace layout (all 16B-aligned: every chunk is a multiple of 32 floats)
    float* w = (float*)d_ws;
    float* p_src  = w; w += kN;
    float* p_dst  = w; w += kN;
    float* qsrc   = w; w += (size_t)kR * kN * kHead;
    float* qdst   = w; w += (size_t)kR * kN * kHead;
    float* V      = w; w += kCols * kIn;
    float* C      = w; w += 32;
    float* hbuf   = w; w += (size_t)kR * kN * kD;
    float* hcat   = w; w += (size_t)kN * kR * kOut;
    float* sign_s = w; w += (size_t)kR * kE;
    float* alpha_s= w; w += (size_t)kR * kE * 4;
    int* srcs_s   = (int*)w; w += (size_t)kR * kE;
    int* deg      = (int*)w; w += kR * kN;
    int* cursor   = (int*)w; w += kR * kN;
    int* rowstart = (int*)w; w += kR * kN;

    k_prep<<<1, 256, 0, stream>>>(Wd, bd, Wf, Ww, bw, Wa, V, C);
    k_node_pre<<<kN / NB, 256, 0, stream>>>(feat, Ww, bw, V, C,
                                            hbuf, p_src, p_dst, qsrc, qdst);

    hipMemsetAsync(deg, 0, 2 * kR * kN * sizeof(int), stream);  // deg + cursor
    k_hist<<<dim3(kE / 256, kR), 256, 0, stream>>>(edges, deg);
    k_scan<<<kR, 1024, 0, stream>>>(deg, rowstart);
    k_scatter<<<dim3(kE / 256, kR), 256, 0, stream>>>(
        edges, p_src, p_dst, qsrc, qdst, bf, ba,
        rowstart, cursor, srcs_s, sign_s, (float4*)alpha_s);
    k_node_agg<<<dim3(kN, kR), 256, 0, stream>>>(
        deg, rowstart, srcs_s, sign_s, (const float4*)alpha_s, hbuf, hcat);

    k_hout<<<kN, 64, 0, stream>>>(hcat, Wl, bl, out);
    k_yhat<<<kN, 256, 0, stream>>>(bi, mask, labels, out + (size_t)kN * kOut);
}